// Round 14
// baseline (7543.405 us; speedup 1.0000x reference)
//
#include <hip/hip_runtime.h>
#include <math.h>

// RNN scan, SEQ=2048, BATCH=64, I=H=O=256, fp32.
// GOLDEN (confirmed round 10, absmax 0.0): XLA-CPU fp32 —
//   dots : per-element single-acc ascending-k FMA chain (Eigen gebp)
//   +bh, +xp : one fadd each
//   tanh : Eigen fast-tanh, clamp +-7.99881172180175781, FMA Horner,
//          exact fdiv, |x|<4e-4 -> x (unclamped).
// DO NOT change op order in K1/K2 — the recurrence is chaotic (gain ~2.5/step).
//
// R14: R10-R13 all compiled to the same shape: compiler reloads Wh in-loop
// with only ~11 loads outstanding (5900 cyc/step). New design: EMBRACE the
// reload — stream Wh from L2 (256KB, XCD-resident) with an explicit 16-phase
// software pipeline, prefetch distance 3 (4 rotating 16-float buffers, all
// indices compile-time). One opaque-pointer asm per step prevents cross-step
// LICM/CSE from re-creating the 256-live-value spill. FMA order unchanged.

#define SEQ 2048
#define BATCH 64
#define HID 256
#define BH 16384  // BATCH*HID

// Eigen/XLA fast-tanh f32, FMA evaluation, clamp 7.99881172180175781.
__device__ __forceinline__ float tanh_xla(float x) {
  const float kClamp = 7.99881172180175781f;
  float xc = fminf(fmaxf(x, -kClamp), kClamp);
  float x2 = __fmul_rn(xc, xc);
  float p = __fmaf_rn(x2, -2.76076847742355e-16f, 2.00018790482477e-13f);
  p = __fmaf_rn(x2, p, -8.60467152213735e-11f);
  p = __fmaf_rn(x2, p, 5.12229709037114e-08f);
  p = __fmaf_rn(x2, p, 1.48572235717979e-05f);
  p = __fmaf_rn(x2, p, 6.37261928875436e-04f);
  p = __fmaf_rn(x2, p, 4.89352455891786e-03f);
  p = __fmul_rn(xc, p);
  float q = __fmaf_rn(x2, 1.19825839466702e-06f, 1.18534705686654e-04f);
  q = __fmaf_rn(x2, q, 2.26843463243900e-03f);
  q = __fmaf_rn(x2, q, 4.89352518554385e-03f);
  float r = __fdiv_rn(p, q);
  return (fabsf(x) < 0.0004f) ? x : r;
}

// ---------------------------------------------------------------------------
// K1: xp = X @ Ux + bh. Per element: single-acc ascending-i FMA chain
// (Eigen order), then one fadd for bias. BIT-EXACT — do not reorder.
// ---------------------------------------------------------------------------
__global__ __launch_bounds__(256) void xp_dot_kernel(
    const float* __restrict__ X, const float* __restrict__ Ux,
    const float* __restrict__ bh, float* __restrict__ XP) {
  __shared__ float xs[8][256];

  const int tid = threadIdx.x;
  const size_t row0 = (size_t)blockIdx.x * 8;

  const float4* src = (const float4*)(X + row0 * 256);
  float4* dst = (float4*)&xs[0][0];
  dst[tid] = src[tid];
  dst[256 + tid] = src[256 + tid];
  __syncthreads();

  const int h = tid;
  float acc[8] = {0.f, 0.f, 0.f, 0.f, 0.f, 0.f, 0.f, 0.f};

#pragma unroll 4
  for (int i = 0; i < 256; ++i) {
    float u = Ux[i * 256 + h];
#pragma unroll
    for (int r = 0; r < 8; ++r)
      acc[r] = __fmaf_rn(xs[r][i], u, acc[r]);   // ascending i, single acc
  }

  const float b = bh[h];
#pragma unroll
  for (int r = 0; r < 8; ++r)
    XP[(row0 + r) * 256 + h] = __fadd_rn(acc[r], b);
}

// ---------------------------------------------------------------------------
// K2: scan. One block per batch row; thread j owns column j. Wh column j is
// STREAMED from L2 each step: 16 phases x 16 k-values, 4 rotating buffers,
// prefetch distance 3 (phase C loads chunk C+3, consumes chunk C). Phases
// 13-15 prefetch next step's chunks 0-2 (weights are step-invariant, so the
// pipeline is seamless). Opaque pointer per step defeats LICM/CSE.
// ---------------------------------------------------------------------------
__global__ __launch_bounds__(256)
__attribute__((amdgpu_waves_per_eu(1, 1)))
void scan_xla_kernel(
    const float* __restrict__ Wh, const float* __restrict__ h0,
    float* __restrict__ xpH, float* __restrict__ hfinal) {
  __shared__ float hbuf0[256];
  __shared__ float hbuf1[256];

  const int b = blockIdx.x;
  const int j = threadIdx.x;

  float wb0[16], wb1[16], wb2[16], wb3[16];  // compile-time indices only

  hbuf0[j] = h0[b * 256 + j];
  __syncthreads();

  float xp_cur = xpH[(size_t)b * 256 + j];  // xp[t=0]
  float hn_prev = 0.f;
  const float* cur = hbuf0;
  float* nxt = hbuf1;

  uintptr_t wpb = (uintptr_t)Wh;

  // Prologue: chunks 0,1,2 -> wb0,wb1,wb2.
  {
    const float* whp = (const float*)wpb;
#pragma unroll
    for (int q = 0; q < 16; ++q) wb0[q] = whp[(0 * 16 + q) * 256 + j];
#pragma unroll
    for (int q = 0; q < 16; ++q) wb1[q] = whp[(1 * 16 + q) * 256 + j];
#pragma unroll
    for (int q = 0; q < 16; ++q) wb2[q] = whp[(2 * 16 + q) * 256 + j];
  }

  for (int t = 0; t < SEQ; ++t) {
    asm volatile("" : "+s"(wpb));        // pointer loop-variant: no cross-step CSE
    const float* whp = (const float*)wpb;

    // h-store / xp-load issued first; retire under the FMA pipeline.
    if (t > 0)
      xpH[(size_t)(t - 1) * BH + b * 256 + j] = hn_prev;
    float xp_next = (t + 1 < SEQ) ? xpH[(size_t)(t + 1) * BH + b * 256 + j] : 0.f;

    float acc = 0.f;
    const float4* h4 = (const float4*)cur;

    // Phase C: load chunk (C+3)&15 into wb[(C+3)%4], FMA chunk C from wb[C%4].
    // FMA order: ascending k, single accumulator — BIT-EXACT.
#define PHASE(C, LB, UB)                                                      \
    {                                                                         \
      _Pragma("unroll")                                                       \
      for (int q = 0; q < 16; ++q)                                            \
        LB[q] = whp[((((C) + 3) & 15) * 16 + q) * 256 + j];                   \
      _Pragma("unroll")                                                       \
      for (int q = 0; q < 4; ++q) {                                           \
        float4 hv = h4[(C) * 4 + q];                                          \
        acc = __fmaf_rn(hv.x, UB[q * 4 + 0], acc);                            \
        acc = __fmaf_rn(hv.y, UB[q * 4 + 1], acc);                            \
        acc = __fmaf_rn(hv.z, UB[q * 4 + 2], acc);                            \
        acc = __fmaf_rn(hv.w, UB[q * 4 + 3], acc);                            \
      }                                                                       \
    }

    PHASE(0,  wb3, wb0)
    PHASE(1,  wb0, wb1)
    PHASE(2,  wb1, wb2)
    PHASE(3,  wb2, wb3)
    PHASE(4,  wb3, wb0)
    PHASE(5,  wb0, wb1)
    PHASE(6,  wb1, wb2)
    PHASE(7,  wb2, wb3)
    PHASE(8,  wb3, wb0)
    PHASE(9,  wb0, wb1)
    PHASE(10, wb1, wb2)
    PHASE(11, wb2, wb3)
    PHASE(12, wb3, wb0)
    PHASE(13, wb0, wb1)   // prefetches next step's chunk 0
    PHASE(14, wb1, wb2)   // next step's chunk 1
    PHASE(15, wb2, wb3)   // next step's chunk 2
#undef PHASE

    float z = __fadd_rn(xp_cur, acc);
    float hn = tanh_xla(z);

    nxt[j] = hn;
    __syncthreads();      // one barrier per step (double-buffered h)

    const float* tmp = cur; cur = nxt; nxt = (float*)tmp;
    xp_cur = xp_next;
    hn_prev = hn;
  }

  xpH[(size_t)(SEQ - 1) * BH + b * 256 + j] = hn_prev;
  hfinal[b * 256 + j] = hn_prev;
}

// ---------------------------------------------------------------------------
// K3: in-place fp32 GEMM: rows of HO (M x 256) -> row @ Vo + co.
// Outside the feedback loop => rounding free. Block stages its own 64 rows
// in LDS then overwrites exactly those rows (race-free).
// ---------------------------------------------------------------------------
__global__ __launch_bounds__(256) void gemm_inplace_kernel(
    float* __restrict__ HO, const float* __restrict__ Vo,
    const float* __restrict__ co) {
  __shared__ float Hs[64][260];
  __shared__ float Bs[32][64];

  const int tid = threadIdx.x;
  const int bm = blockIdx.x;
  float* base = HO + (size_t)bm * 64 * 256;

#pragma unroll
  for (int l = 0; l < 16; ++l) {
    int idx = l * 256 + tid;
    int r = idx >> 6;
    int c4 = idx & 63;
    float4 v = *(const float4*)&base[r * 256 + c4 * 4];
    *(float4*)&Hs[r][c4 * 4] = v;
  }

  const int tr = tid >> 4;
  const int tc = tid & 15;

  for (int bn = 0; bn < 4; ++bn) {
    float acc[4][4];
#pragma unroll
    for (int i = 0; i < 4; ++i)
#pragma unroll
      for (int j = 0; j < 4; ++j) acc[i][j] = 0.f;

    for (int kt = 0; kt < 256; kt += 32) {
      __syncthreads();
#pragma unroll
      for (int l = 0; l < 2; ++l) {
        int idx = tid * 2 + l;
        int k2 = idx >> 4;
        int nn = (idx & 15) << 2;
        float4 bv = *(const float4*)&Vo[(size_t)(kt + k2) * 256 + bn * 64 + nn];
        *(float4*)&Bs[k2][nn] = bv;
      }
      __syncthreads();
#pragma unroll
      for (int k = 0; k < 32; ++k) {
        float4 bq = *(const float4*)&Bs[k][tc * 4];
        float bv[4] = {bq.x, bq.y, bq.z, bq.w};
#pragma unroll
        for (int i = 0; i < 4; ++i) {
          float a = Hs[tr * 4 + i][kt + k];
#pragma unroll
          for (int j = 0; j < 4; ++j) acc[i][j] += a * bv[j];
        }
      }
    }

    const float4 cb = *(const float4*)&co[bn * 64 + tc * 4];
    const float cv[4] = {cb.x, cb.y, cb.z, cb.w};
#pragma unroll
    for (int i = 0; i < 4; ++i) {
      float4 o;
      o.x = acc[i][0] + cv[0];
      o.y = acc[i][1] + cv[1];
      o.z = acc[i][2] + cv[2];
      o.w = acc[i][3] + cv[3];
      *(float4*)&base[(tr * 4 + i) * 256 + bn * 64 + tc * 4] = o;
    }
  }
}

extern "C" void kernel_launch(void* const* d_in, const int* in_sizes, int n_in,
                              void* d_out, int out_size, void* d_ws, size_t ws_size,
                              hipStream_t stream) {
  const float* inputs = (const float*)d_in[0];
  const float* h0     = (const float*)d_in[1];
  const float* Wh     = (const float*)d_in[2];
  const float* Ux     = (const float*)d_in[3];
  const float* bh     = (const float*)d_in[4];
  const float* Vo     = (const float*)d_in[5];
  const float* co     = (const float*)d_in[6];

  float* out = (float*)d_out;                       // outputs (S,B,O)
  float* hfinal = out + (size_t)SEQ * BATCH * 256;  // ht_final (B,H)
  (void)d_ws; (void)ws_size;

  const int M = SEQ * BATCH;  // 131072 rows

  // K1: xp (Eigen-order FMA chain + bias add) -> d_out outputs region
  xp_dot_kernel<<<M / 8, 256, 0, stream>>>(inputs, Ux, bh, out);

  // K2: XLA-exact scan, Wh streamed from L2 via 16-phase pipeline.
  scan_xla_kernel<<<BATCH, 256, 0, stream>>>(Wh, h0, out, hfinal);

  // K3: in-place outputs = H @ Vo + co.
  gemm_inplace_kernel<<<M / 64, 256, 0, stream>>>(out, Vo, co);
}

// Round 15
// 5980.717 us; speedup vs baseline: 1.2613x; 1.2613x over previous
//
#include <hip/hip_runtime.h>
#include <math.h>

// RNN scan, SEQ=2048, BATCH=64, I=H=O=256, fp32.
// GOLDEN (confirmed round 10, absmax 0.0): XLA-CPU fp32 —
//   dots : per-element single-acc ascending-k FMA chain (Eigen gebp)
//   +bh, +xp : one fadd each
//   tanh : Eigen fast-tanh, clamp +-7.99881172180175781, FMA Horner,
//          exact fdiv, |x|<4e-4 -> x (unclamped).
// DO NOT change op order in K1/K2 — the recurrence is chaotic (gain ~2.5/step).
//
// R15: R10-R14 post-mortems: the register allocator REMATERIALIZES the 256
// loop-invariant Wh loads (re-reads L2 every step, ~4400 cyc stall) no matter
// the source form, and explicit streaming pipelines serialize on vmcnt.
// Fix: store Wh[:,j] in 256 AGPRs via explicit v_accvgpr_write/read inline
// asm — register-file residence the compiler cannot undo. AGPR<->VGPR moves
// are 1-cyc register ops that fill the FMA dep-chain gaps.

#define SEQ 2048
#define BATCH 64
#define HID 256
#define BH 16384  // BATCH*HID

// Eigen/XLA fast-tanh f32, FMA evaluation, clamp 7.99881172180175781.
__device__ __forceinline__ float tanh_xla(float x) {
  const float kClamp = 7.99881172180175781f;
  float xc = fminf(fmaxf(x, -kClamp), kClamp);
  float x2 = __fmul_rn(xc, xc);
  float p = __fmaf_rn(x2, -2.76076847742355e-16f, 2.00018790482477e-13f);
  p = __fmaf_rn(x2, p, -8.60467152213735e-11f);
  p = __fmaf_rn(x2, p, 5.12229709037114e-08f);
  p = __fmaf_rn(x2, p, 1.48572235717979e-05f);
  p = __fmaf_rn(x2, p, 6.37261928875436e-04f);
  p = __fmaf_rn(x2, p, 4.89352455891786e-03f);
  p = __fmul_rn(xc, p);
  float q = __fmaf_rn(x2, 1.19825839466702e-06f, 1.18534705686654e-04f);
  q = __fmaf_rn(x2, q, 2.26843463243900e-03f);
  q = __fmaf_rn(x2, q, 4.89352518554385e-03f);
  float r = __fdiv_rn(p, q);
  return (fabsf(x) < 0.0004f) ? x : r;
}

// ---------------------------------------------------------------------------
// K1: xp = X @ Ux + bh. Per element: single-acc ascending-i FMA chain
// (Eigen order), then one fadd for bias. BIT-EXACT — do not reorder.
// ---------------------------------------------------------------------------
__global__ __launch_bounds__(256) void xp_dot_kernel(
    const float* __restrict__ X, const float* __restrict__ Ux,
    const float* __restrict__ bh, float* __restrict__ XP) {
  __shared__ float xs[8][256];

  const int tid = threadIdx.x;
  const size_t row0 = (size_t)blockIdx.x * 8;

  const float4* src = (const float4*)(X + row0 * 256);
  float4* dst = (float4*)&xs[0][0];
  dst[tid] = src[tid];
  dst[256 + tid] = src[256 + tid];
  __syncthreads();

  const int h = tid;
  float acc[8] = {0.f, 0.f, 0.f, 0.f, 0.f, 0.f, 0.f, 0.f};

#pragma unroll 4
  for (int i = 0; i < 256; ++i) {
    float u = Ux[i * 256 + h];
#pragma unroll
    for (int r = 0; r < 8; ++r)
      acc[r] = __fmaf_rn(xs[r][i], u, acc[r]);   // ascending i, single acc
  }

  const float b = bh[h];
#pragma unroll
  for (int r = 0; r < 8; ++r)
    XP[(row0 + r) * 256 + h] = __fadd_rn(acc[r], b);
}

// ---------------------------------------------------------------------------
// K2: scan. One block per batch row; thread j owns column j. Wh[:,j] lives in
// AGPRs a0..a255 (explicit accvgpr write/read asm). h double-buffered in LDS,
// one barrier/step. FMA chain: ascending k, single acc — BIT-EXACT.
// ---------------------------------------------------------------------------
// Load weight K into aK at init (coalesced across j).
#define WLD(K) { float wt = Wh[(K) * 256 + j]; \
  asm volatile("v_accvgpr_write_b32 a" #K ", %0" :: "v"(wt) : "a" #K); }
#define WLD4(K0,K1,K2,K3) WLD(K0) WLD(K1) WLD(K2) WLD(K3)

// Read aK into a fresh VGPR (1-cyc reg-reg move; volatile => in-loop, no CSE).
#define WRD(K, D) asm volatile("v_accvgpr_read_b32 %0, a" #K : "=v"(D));

// One float4 of h (LDS broadcast) x 4 AGPR weights -> 4 chain FMAs.
#define STEP4(Q, K0,K1,K2,K3) { \
  float4 hv = h4[Q]; float w0_, w1_, w2_, w3_; \
  WRD(K0, w0_) WRD(K1, w1_) WRD(K2, w2_) WRD(K3, w3_) \
  acc = __fmaf_rn(hv.x, w0_, acc); \
  acc = __fmaf_rn(hv.y, w1_, acc); \
  acc = __fmaf_rn(hv.z, w2_, acc); \
  acc = __fmaf_rn(hv.w, w3_, acc); }

__global__ __launch_bounds__(256)
__attribute__((amdgpu_waves_per_eu(1, 1)))
void scan_xla_kernel(
    const float* __restrict__ Wh, const float* __restrict__ h0,
    float* __restrict__ xpH, float* __restrict__ hfinal) {
  __shared__ float hbuf0[256];
  __shared__ float hbuf1[256];

  const int b = blockIdx.x;
  const int j = threadIdx.x;

  // ---- load Wh[:,j] into a0..a255 ----
  WLD4(0,1,2,3)       WLD4(4,5,6,7)       WLD4(8,9,10,11)     WLD4(12,13,14,15)
  WLD4(16,17,18,19)   WLD4(20,21,22,23)   WLD4(24,25,26,27)   WLD4(28,29,30,31)
  WLD4(32,33,34,35)   WLD4(36,37,38,39)   WLD4(40,41,42,43)   WLD4(44,45,46,47)
  WLD4(48,49,50,51)   WLD4(52,53,54,55)   WLD4(56,57,58,59)   WLD4(60,61,62,63)
  WLD4(64,65,66,67)   WLD4(68,69,70,71)   WLD4(72,73,74,75)   WLD4(76,77,78,79)
  WLD4(80,81,82,83)   WLD4(84,85,86,87)   WLD4(88,89,90,91)   WLD4(92,93,94,95)
  WLD4(96,97,98,99)   WLD4(100,101,102,103) WLD4(104,105,106,107) WLD4(108,109,110,111)
  WLD4(112,113,114,115) WLD4(116,117,118,119) WLD4(120,121,122,123) WLD4(124,125,126,127)
  WLD4(128,129,130,131) WLD4(132,133,134,135) WLD4(136,137,138,139) WLD4(140,141,142,143)
  WLD4(144,145,146,147) WLD4(148,149,150,151) WLD4(152,153,154,155) WLD4(156,157,158,159)
  WLD4(160,161,162,163) WLD4(164,165,166,167) WLD4(168,169,170,171) WLD4(172,173,174,175)
  WLD4(176,177,178,179) WLD4(180,181,182,183) WLD4(184,185,186,187) WLD4(188,189,190,191)
  WLD4(192,193,194,195) WLD4(196,197,198,199) WLD4(200,201,202,203) WLD4(204,205,206,207)
  WLD4(208,209,210,211) WLD4(212,213,214,215) WLD4(216,217,218,219) WLD4(220,221,222,223)
  WLD4(224,225,226,227) WLD4(228,229,230,231) WLD4(232,233,234,235) WLD4(236,237,238,239)
  WLD4(240,241,242,243) WLD4(244,245,246,247) WLD4(248,249,250,251) WLD4(252,253,254,255)

  hbuf0[j] = h0[b * 256 + j];
  __syncthreads();

  float xp_cur = xpH[(size_t)b * 256 + j];  // xp[t=0]
  float hn_prev = 0.f;
  const float* cur = hbuf0;
  float* nxt = hbuf1;

  for (int t = 0; t < SEQ; ++t) {
    // h-store / xp-load issued first; retire under the FMA chain.
    if (t > 0)
      xpH[(size_t)(t - 1) * BH + b * 256 + j] = hn_prev;
    float xp_next = (t + 1 < SEQ) ? xpH[(size_t)(t + 1) * BH + b * 256 + j] : 0.f;

    float acc = 0.f;
    const float4* h4 = (const float4*)cur;

    STEP4(0, 0,1,2,3)       STEP4(1, 4,5,6,7)       STEP4(2, 8,9,10,11)     STEP4(3, 12,13,14,15)
    STEP4(4, 16,17,18,19)   STEP4(5, 20,21,22,23)   STEP4(6, 24,25,26,27)   STEP4(7, 28,29,30,31)
    STEP4(8, 32,33,34,35)   STEP4(9, 36,37,38,39)   STEP4(10, 40,41,42,43)  STEP4(11, 44,45,46,47)
    STEP4(12, 48,49,50,51)  STEP4(13, 52,53,54,55)  STEP4(14, 56,57,58,59)  STEP4(15, 60,61,62,63)
    STEP4(16, 64,65,66,67)  STEP4(17, 68,69,70,71)  STEP4(18, 72,73,74,75)  STEP4(19, 76,77,78,79)
    STEP4(20, 80,81,82,83)  STEP4(21, 84,85,86,87)  STEP4(22, 88,89,90,91)  STEP4(23, 92,93,94,95)
    STEP4(24, 96,97,98,99)  STEP4(25, 100,101,102,103) STEP4(26, 104,105,106,107) STEP4(27, 108,109,110,111)
    STEP4(28, 112,113,114,115) STEP4(29, 116,117,118,119) STEP4(30, 120,121,122,123) STEP4(31, 124,125,126,127)
    STEP4(32, 128,129,130,131) STEP4(33, 132,133,134,135) STEP4(34, 136,137,138,139) STEP4(35, 140,141,142,143)
    STEP4(36, 144,145,146,147) STEP4(37, 148,149,150,151) STEP4(38, 152,153,154,155) STEP4(39, 156,157,158,159)
    STEP4(40, 160,161,162,163) STEP4(41, 164,165,166,167) STEP4(42, 168,169,170,171) STEP4(43, 172,173,174,175)
    STEP4(44, 176,177,178,179) STEP4(45, 180,181,182,183) STEP4(46, 184,185,186,187) STEP4(47, 188,189,190,191)
    STEP4(48, 192,193,194,195) STEP4(49, 196,197,198,199) STEP4(50, 200,201,202,203) STEP4(51, 204,205,206,207)
    STEP4(52, 208,209,210,211) STEP4(53, 212,213,214,215) STEP4(54, 216,217,218,219) STEP4(55, 220,221,222,223)
    STEP4(56, 224,225,226,227) STEP4(57, 228,229,230,231) STEP4(58, 232,233,234,235) STEP4(59, 236,237,238,239)
    STEP4(60, 240,241,242,243) STEP4(61, 244,245,246,247) STEP4(62, 248,249,250,251) STEP4(63, 252,253,254,255)

    float z = __fadd_rn(xp_cur, acc);
    float hn = tanh_xla(z);

    nxt[j] = hn;
    __syncthreads();      // one barrier per step (double-buffered h)

    const float* tmp = cur; cur = nxt; nxt = (float*)tmp;
    xp_cur = xp_next;
    hn_prev = hn;
  }

  xpH[(size_t)(SEQ - 1) * BH + b * 256 + j] = hn_prev;
  hfinal[b * 256 + j] = hn_prev;
}

// ---------------------------------------------------------------------------
// K3: in-place fp32 GEMM: rows of HO (M x 256) -> row @ Vo + co.
// Outside the feedback loop => rounding free. Block stages its own 64 rows
// in LDS then overwrites exactly those rows (race-free).
// ---------------------------------------------------------------------------
__global__ __launch_bounds__(256) void gemm_inplace_kernel(
    float* __restrict__ HO, const float* __restrict__ Vo,
    const float* __restrict__ co) {
  __shared__ float Hs[64][260];
  __shared__ float Bs[32][64];

  const int tid = threadIdx.x;
  const int bm = blockIdx.x;
  float* base = HO + (size_t)bm * 64 * 256;

#pragma unroll
  for (int l = 0; l < 16; ++l) {
    int idx = l * 256 + tid;
    int r = idx >> 6;
    int c4 = idx & 63;
    float4 v = *(const float4*)&base[r * 256 + c4 * 4];
    *(float4*)&Hs[r][c4 * 4] = v;
  }

  const int tr = tid >> 4;
  const int tc = tid & 15;

  for (int bn = 0; bn < 4; ++bn) {
    float acc[4][4];
#pragma unroll
    for (int i = 0; i < 4; ++i)
#pragma unroll
      for (int j = 0; j < 4; ++j) acc[i][j] = 0.f;

    for (int kt = 0; kt < 256; kt += 32) {
      __syncthreads();
#pragma unroll
      for (int l = 0; l < 2; ++l) {
        int idx = tid * 2 + l;
        int k2 = idx >> 4;
        int nn = (idx & 15) << 2;
        float4 bv = *(const float4*)&Vo[(size_t)(kt + k2) * 256 + bn * 64 + nn];
        *(float4*)&Bs[k2][nn] = bv;
      }
      __syncthreads();
#pragma unroll
      for (int k = 0; k < 32; ++k) {
        float4 bq = *(const float4*)&Bs[k][tc * 4];
        float bv[4] = {bq.x, bq.y, bq.z, bq.w};
#pragma unroll
        for (int i = 0; i < 4; ++i) {
          float a = Hs[tr * 4 + i][kt + k];
#pragma unroll
          for (int j = 0; j < 4; ++j) acc[i][j] += a * bv[j];
        }
      }
    }

    const float4 cb = *(const float4*)&co[bn * 64 + tc * 4];
    const float cv[4] = {cb.x, cb.y, cb.z, cb.w};
#pragma unroll
    for (int i = 0; i < 4; ++i) {
      float4 o;
      o.x = acc[i][0] + cv[0];
      o.y = acc[i][1] + cv[1];
      o.z = acc[i][2] + cv[2];
      o.w = acc[i][3] + cv[3];
      *(float4*)&base[(tr * 4 + i) * 256 + bn * 64 + tc * 4] = o;
    }
  }
}

extern "C" void kernel_launch(void* const* d_in, const int* in_sizes, int n_in,
                              void* d_out, int out_size, void* d_ws, size_t ws_size,
                              hipStream_t stream) {
  const float* inputs = (const float*)d_in[0];
  const float* h0     = (const float*)d_in[1];
  const float* Wh     = (const float*)d_in[2];
  const float* Ux     = (const float*)d_in[3];
  const float* bh     = (const float*)d_in[4];
  const float* Vo     = (const float*)d_in[5];
  const float* co     = (const float*)d_in[6];

  float* out = (float*)d_out;                       // outputs (S,B,O)
  float* hfinal = out + (size_t)SEQ * BATCH * 256;  // ht_final (B,H)
  (void)d_ws; (void)ws_size;

  const int M = SEQ * BATCH;  // 131072 rows

  // K1: xp (Eigen-order FMA chain + bias add) -> d_out outputs region
  xp_dot_kernel<<<M / 8, 256, 0, stream>>>(inputs, Ux, bh, out);

  // K2: XLA-exact scan, Wh pinned in AGPRs.
  scan_xla_kernel<<<BATCH, 256, 0, stream>>>(Wh, h0, out, hfinal);

  // K3: in-place outputs = H @ Vo + co.
  gemm_inplace_kernel<<<M / 64, 256, 0, stream>>>(out, Vo, co);
}

// Round 16
// 3815.094 us; speedup vs baseline: 1.9773x; 1.5676x over previous
//
#include <hip/hip_runtime.h>
#include <math.h>

// RNN scan, SEQ=2048, BATCH=64, I=H=O=256, fp32.
// GOLDEN (confirmed round 10, absmax 0.0): XLA-CPU fp32 —
//   dots : per-element single-acc ascending-k FMA chain (Eigen gebp)
//   +bh, +xp : one fadd each
//   tanh : Eigen fast-tanh, clamp +-7.99881172180175781, FMA Horner,
//          exact fdiv, |x|<4e-4 -> x (unclamped).
// DO NOT change op order in K1/K2 — the recurrence is chaotic (gain ~2.5/step).
//
// R16: R15 post-mortem — weights were never the stall (AGPR removed weight
// traffic, time unchanged). Residual ~4000 cyc/step = LDS h-read latency
// exposed inside the serial chain (reads scheduled near uses; 256 volatile
// fences blocked hoisting). Fix: distance-8 software pipeline of ds_reads
// via 8 rotating NAMED float4 buffers (in program order, so in-order issue
// guarantees depth), AGPR reads batched 4/asm (64 fences not 256).

#define SEQ 2048
#define BATCH 64
#define HID 256
#define BH 16384  // BATCH*HID

// Eigen/XLA fast-tanh f32, FMA evaluation, clamp 7.99881172180175781.
__device__ __forceinline__ float tanh_xla(float x) {
  const float kClamp = 7.99881172180175781f;
  float xc = fminf(fmaxf(x, -kClamp), kClamp);
  float x2 = __fmul_rn(xc, xc);
  float p = __fmaf_rn(x2, -2.76076847742355e-16f, 2.00018790482477e-13f);
  p = __fmaf_rn(x2, p, -8.60467152213735e-11f);
  p = __fmaf_rn(x2, p, 5.12229709037114e-08f);
  p = __fmaf_rn(x2, p, 1.48572235717979e-05f);
  p = __fmaf_rn(x2, p, 6.37261928875436e-04f);
  p = __fmaf_rn(x2, p, 4.89352455891786e-03f);
  p = __fmul_rn(xc, p);
  float q = __fmaf_rn(x2, 1.19825839466702e-06f, 1.18534705686654e-04f);
  q = __fmaf_rn(x2, q, 2.26843463243900e-03f);
  q = __fmaf_rn(x2, q, 4.89352518554385e-03f);
  float r = __fdiv_rn(p, q);
  return (fabsf(x) < 0.0004f) ? x : r;
}

// ---------------------------------------------------------------------------
// K1: xp = X @ Ux + bh. Per element: single-acc ascending-i FMA chain
// (Eigen order), then one fadd for bias. BIT-EXACT — do not reorder.
// ---------------------------------------------------------------------------
__global__ __launch_bounds__(256) void xp_dot_kernel(
    const float* __restrict__ X, const float* __restrict__ Ux,
    const float* __restrict__ bh, float* __restrict__ XP) {
  __shared__ float xs[8][256];

  const int tid = threadIdx.x;
  const size_t row0 = (size_t)blockIdx.x * 8;

  const float4* src = (const float4*)(X + row0 * 256);
  float4* dst = (float4*)&xs[0][0];
  dst[tid] = src[tid];
  dst[256 + tid] = src[256 + tid];
  __syncthreads();

  const int h = tid;
  float acc[8] = {0.f, 0.f, 0.f, 0.f, 0.f, 0.f, 0.f, 0.f};

#pragma unroll 4
  for (int i = 0; i < 256; ++i) {
    float u = Ux[i * 256 + h];
#pragma unroll
    for (int r = 0; r < 8; ++r)
      acc[r] = __fmaf_rn(xs[r][i], u, acc[r]);   // ascending i, single acc
  }

  const float b = bh[h];
#pragma unroll
  for (int r = 0; r < 8; ++r)
    XP[(row0 + r) * 256 + h] = __fadd_rn(acc[r], b);
}

// ---------------------------------------------------------------------------
// K2: scan. One block per batch row; thread j owns column j. Wh[:,j] in AGPRs
// a0..a255 (proven R15). h reads pipelined at distance 8 via named float4
// buffers hb0..hb7. FMA chain: ascending k, single acc — BIT-EXACT.
// ---------------------------------------------------------------------------
#define WLD(K) { float wt = Wh[(K) * 256 + j]; \
  asm volatile("v_accvgpr_write_b32 a" #K ", %0" :: "v"(wt) : "a" #K); }
#define WLD4(K0,K1,K2,K3) WLD(K0) WLD(K1) WLD(K2) WLD(K3)

// Batched AGPR->VGPR reads: 4 per asm (fewer scheduler fences).
#define WRD4(K0,K1,K2,K3, D0,D1,D2,D3) \
  asm volatile("v_accvgpr_read_b32 %0, a" #K0 "\n\t" \
               "v_accvgpr_read_b32 %1, a" #K1 "\n\t" \
               "v_accvgpr_read_b32 %2, a" #K2 "\n\t" \
               "v_accvgpr_read_b32 %3, a" #K3 \
               : "=v"(D0), "=v"(D1), "=v"(D2), "=v"(D3));

// Chunk with refill: consume BUF (4 chain FMAs), then refill BUF from h4[NQ]
// (read lands 8 chunks later => ~112 cyc of issue distance covers LDS latency).
#define STEPL(BUF, K0,K1,K2,K3, NQ) { \
  float w0_,w1_,w2_,w3_; \
  WRD4(K0,K1,K2,K3, w0_,w1_,w2_,w3_) \
  acc = __fmaf_rn(BUF.x, w0_, acc); \
  acc = __fmaf_rn(BUF.y, w1_, acc); \
  acc = __fmaf_rn(BUF.z, w2_, acc); \
  acc = __fmaf_rn(BUF.w, w3_, acc); \
  BUF = h4[NQ]; }

#define STEPN(BUF, K0,K1,K2,K3) { \
  float w0_,w1_,w2_,w3_; \
  WRD4(K0,K1,K2,K3, w0_,w1_,w2_,w3_) \
  acc = __fmaf_rn(BUF.x, w0_, acc); \
  acc = __fmaf_rn(BUF.y, w1_, acc); \
  acc = __fmaf_rn(BUF.z, w2_, acc); \
  acc = __fmaf_rn(BUF.w, w3_, acc); }

__global__ __launch_bounds__(256)
__attribute__((amdgpu_waves_per_eu(1, 1)))
void scan_xla_kernel(
    const float* __restrict__ Wh, const float* __restrict__ h0,
    float* __restrict__ xpH, float* __restrict__ hfinal) {
  __shared__ float hbuf0[256];
  __shared__ float hbuf1[256];

  const int b = blockIdx.x;
  const int j = threadIdx.x;

  // ---- load Wh[:,j] into a0..a255 ----
  WLD4(0,1,2,3)       WLD4(4,5,6,7)       WLD4(8,9,10,11)     WLD4(12,13,14,15)
  WLD4(16,17,18,19)   WLD4(20,21,22,23)   WLD4(24,25,26,27)   WLD4(28,29,30,31)
  WLD4(32,33,34,35)   WLD4(36,37,38,39)   WLD4(40,41,42,43)   WLD4(44,45,46,47)
  WLD4(48,49,50,51)   WLD4(52,53,54,55)   WLD4(56,57,58,59)   WLD4(60,61,62,63)
  WLD4(64,65,66,67)   WLD4(68,69,70,71)   WLD4(72,73,74,75)   WLD4(76,77,78,79)
  WLD4(80,81,82,83)   WLD4(84,85,86,87)   WLD4(88,89,90,91)   WLD4(92,93,94,95)
  WLD4(96,97,98,99)   WLD4(100,101,102,103) WLD4(104,105,106,107) WLD4(108,109,110,111)
  WLD4(112,113,114,115) WLD4(116,117,118,119) WLD4(120,121,122,123) WLD4(124,125,126,127)
  WLD4(128,129,130,131) WLD4(132,133,134,135) WLD4(136,137,138,139) WLD4(140,141,142,143)
  WLD4(144,145,146,147) WLD4(148,149,150,151) WLD4(152,153,154,155) WLD4(156,157,158,159)
  WLD4(160,161,162,163) WLD4(164,165,166,167) WLD4(168,169,170,171) WLD4(172,173,174,175)
  WLD4(176,177,178,179) WLD4(180,181,182,183) WLD4(184,185,186,187) WLD4(188,189,190,191)
  WLD4(192,193,194,195) WLD4(196,197,198,199) WLD4(200,201,202,203) WLD4(204,205,206,207)
  WLD4(208,209,210,211) WLD4(212,213,214,215) WLD4(216,217,218,219) WLD4(220,221,222,223)
  WLD4(224,225,226,227) WLD4(228,229,230,231) WLD4(232,233,234,235) WLD4(236,237,238,239)
  WLD4(240,241,242,243) WLD4(244,245,246,247) WLD4(248,249,250,251) WLD4(252,253,254,255)

  hbuf0[j] = h0[b * 256 + j];
  __syncthreads();

  float xp_cur = xpH[(size_t)b * 256 + j];  // xp[t=0]
  float hn_prev = 0.f;
  const float* cur = hbuf0;
  float* nxt = hbuf1;

  for (int t = 0; t < SEQ; ++t) {
    // Global store/load issued first; retire under the chain (vmcnt slack).
    if (t > 0)
      xpH[(size_t)(t - 1) * BH + b * 256 + j] = hn_prev;
    float xp_next = (t + 1 < SEQ) ? xpH[(size_t)(t + 1) * BH + b * 256 + j] : 0.f;

    const float4* h4 = (const float4*)cur;
    // Prologue: fill the 8-deep pipeline.
    float4 hb0 = h4[0], hb1 = h4[1], hb2 = h4[2], hb3 = h4[3];
    float4 hb4 = h4[4], hb5 = h4[5], hb6 = h4[6], hb7 = h4[7];

    float acc = 0.f;
    STEPL(hb0, 0,1,2,3, 8)        STEPL(hb1, 4,5,6,7, 9)
    STEPL(hb2, 8,9,10,11, 10)     STEPL(hb3, 12,13,14,15, 11)
    STEPL(hb4, 16,17,18,19, 12)   STEPL(hb5, 20,21,22,23, 13)
    STEPL(hb6, 24,25,26,27, 14)   STEPL(hb7, 28,29,30,31, 15)
    STEPL(hb0, 32,33,34,35, 16)   STEPL(hb1, 36,37,38,39, 17)
    STEPL(hb2, 40,41,42,43, 18)   STEPL(hb3, 44,45,46,47, 19)
    STEPL(hb4, 48,49,50,51, 20)   STEPL(hb5, 52,53,54,55, 21)
    STEPL(hb6, 56,57,58,59, 22)   STEPL(hb7, 60,61,62,63, 23)
    STEPL(hb0, 64,65,66,67, 24)   STEPL(hb1, 68,69,70,71, 25)
    STEPL(hb2, 72,73,74,75, 26)   STEPL(hb3, 76,77,78,79, 27)
    STEPL(hb4, 80,81,82,83, 28)   STEPL(hb5, 84,85,86,87, 29)
    STEPL(hb6, 88,89,90,91, 30)   STEPL(hb7, 92,93,94,95, 31)
    STEPL(hb0, 96,97,98,99, 32)   STEPL(hb1, 100,101,102,103, 33)
    STEPL(hb2, 104,105,106,107, 34) STEPL(hb3, 108,109,110,111, 35)
    STEPL(hb4, 112,113,114,115, 36) STEPL(hb5, 116,117,118,119, 37)
    STEPL(hb6, 120,121,122,123, 38) STEPL(hb7, 124,125,126,127, 39)
    STEPL(hb0, 128,129,130,131, 40) STEPL(hb1, 132,133,134,135, 41)
    STEPL(hb2, 136,137,138,139, 42) STEPL(hb3, 140,141,142,143, 43)
    STEPL(hb4, 144,145,146,147, 44) STEPL(hb5, 148,149,150,151, 45)
    STEPL(hb6, 152,153,154,155, 46) STEPL(hb7, 156,157,158,159, 47)
    STEPL(hb0, 160,161,162,163, 48) STEPL(hb1, 164,165,166,167, 49)
    STEPL(hb2, 168,169,170,171, 50) STEPL(hb3, 172,173,174,175, 51)
    STEPL(hb4, 176,177,178,179, 52) STEPL(hb5, 180,181,182,183, 53)
    STEPL(hb6, 184,185,186,187, 54) STEPL(hb7, 188,189,190,191, 55)
    STEPL(hb0, 192,193,194,195, 56) STEPL(hb1, 196,197,198,199, 57)
    STEPL(hb2, 200,201,202,203, 58) STEPL(hb3, 204,205,206,207, 59)
    STEPL(hb4, 208,209,210,211, 60) STEPL(hb5, 212,213,214,215, 61)
    STEPL(hb6, 216,217,218,219, 62) STEPL(hb7, 220,221,222,223, 63)
    STEPN(hb0, 224,225,226,227)   STEPN(hb1, 228,229,230,231)
    STEPN(hb2, 232,233,234,235)   STEPN(hb3, 236,237,238,239)
    STEPN(hb4, 240,241,242,243)   STEPN(hb5, 244,245,246,247)
    STEPN(hb6, 248,249,250,251)   STEPN(hb7, 252,253,254,255)

    float z = __fadd_rn(xp_cur, acc);
    float hn = tanh_xla(z);

    nxt[j] = hn;
    __syncthreads();      // one barrier per step (double-buffered h)

    const float* tmp = cur; cur = nxt; nxt = (float*)tmp;
    xp_cur = xp_next;
    hn_prev = hn;
  }

  xpH[(size_t)(SEQ - 1) * BH + b * 256 + j] = hn_prev;
  hfinal[b * 256 + j] = hn_prev;
}

// ---------------------------------------------------------------------------
// K3: in-place fp32 GEMM: rows of HO (M x 256) -> row @ Vo + co.
// Outside the feedback loop => rounding free. Block stages its own 64 rows
// in LDS then overwrites exactly those rows (race-free).
// ---------------------------------------------------------------------------
__global__ __launch_bounds__(256) void gemm_inplace_kernel(
    float* __restrict__ HO, const float* __restrict__ Vo,
    const float* __restrict__ co) {
  __shared__ float Hs[64][260];
  __shared__ float Bs[32][64];

  const int tid = threadIdx.x;
  const int bm = blockIdx.x;
  float* base = HO + (size_t)bm * 64 * 256;

#pragma unroll
  for (int l = 0; l < 16; ++l) {
    int idx = l * 256 + tid;
    int r = idx >> 6;
    int c4 = idx & 63;
    float4 v = *(const float4*)&base[r * 256 + c4 * 4];
    *(float4*)&Hs[r][c4 * 4] = v;
  }

  const int tr = tid >> 4;
  const int tc = tid & 15;

  for (int bn = 0; bn < 4; ++bn) {
    float acc[4][4];
#pragma unroll
    for (int i = 0; i < 4; ++i)
#pragma unroll
      for (int j = 0; j < 4; ++j) acc[i][j] = 0.f;

    for (int kt = 0; kt < 256; kt += 32) {
      __syncthreads();
#pragma unroll
      for (int l = 0; l < 2; ++l) {
        int idx = tid * 2 + l;
        int k2 = idx >> 4;
        int nn = (idx & 15) << 2;
        float4 bv = *(const float4*)&Vo[(size_t)(kt + k2) * 256 + bn * 64 + nn];
        *(float4*)&Bs[k2][nn] = bv;
      }
      __syncthreads();
#pragma unroll
      for (int k = 0; k < 32; ++k) {
        float4 bq = *(const float4*)&Bs[k][tc * 4];
        float bv[4] = {bq.x, bq.y, bq.z, bq.w};
#pragma unroll
        for (int i = 0; i < 4; ++i) {
          float a = Hs[tr * 4 + i][kt + k];
#pragma unroll
          for (int j = 0; j < 4; ++j) acc[i][j] += a * bv[j];
        }
      }
    }

    const float4 cb = *(const float4*)&co[bn * 64 + tc * 4];
    const float cv[4] = {cb.x, cb.y, cb.z, cb.w};
#pragma unroll
    for (int i = 0; i < 4; ++i) {
      float4 o;
      o.x = acc[i][0] + cv[0];
      o.y = acc[i][1] + cv[1];
      o.z = acc[i][2] + cv[2];
      o.w = acc[i][3] + cv[3];
      *(float4*)&base[(tr * 4 + i) * 256 + bn * 64 + tc * 4] = o;
    }
  }
}

extern "C" void kernel_launch(void* const* d_in, const int* in_sizes, int n_in,
                              void* d_out, int out_size, void* d_ws, size_t ws_size,
                              hipStream_t stream) {
  const float* inputs = (const float*)d_in[0];
  const float* h0     = (const float*)d_in[1];
  const float* Wh     = (const float*)d_in[2];
  const float* Ux     = (const float*)d_in[3];
  const float* bh     = (const float*)d_in[4];
  const float* Vo     = (const float*)d_in[5];
  const float* co     = (const float*)d_in[6];

  float* out = (float*)d_out;                       // outputs (S,B,O)
  float* hfinal = out + (size_t)SEQ * BATCH * 256;  // ht_final (B,H)
  (void)d_ws; (void)ws_size;

  const int M = SEQ * BATCH;  // 131072 rows

  // K1: xp (Eigen-order FMA chain + bias add) -> d_out outputs region
  xp_dot_kernel<<<M / 8, 256, 0, stream>>>(inputs, Ux, bh, out);

  // K2: XLA-exact scan, AGPR weights + distance-8 LDS pipeline.
  scan_xla_kernel<<<BATCH, 256, 0, stream>>>(Wh, h0, out, hfinal);

  // K3: in-place outputs = H @ Vo + co.
  gemm_inplace_kernel<<<M / 64, 256, 0, stream>>>(out, Vo, co);
}

// Round 17
// 3802.842 us; speedup vs baseline: 1.9836x; 1.0032x over previous
//
#include <hip/hip_runtime.h>
#include <math.h>

// RNN scan, SEQ=2048, BATCH=64, I=H=O=256, fp32.
// GOLDEN (confirmed round 10, absmax 0.0): XLA-CPU fp32 —
//   dots : per-element single-acc ascending-k FMA chain (Eigen gebp)
//   +bh, +xp : one fadd each
//   tanh : Eigen fast-tanh, clamp +-7.99881172180175781, FMA Horner,
//          exact fdiv, |x|<4e-4 -> x (unclamped).
// DO NOT change op order in K1/K2 — the recurrence is chaotic (gain ~2.5/step).
//
// R17: R16 (3125us) = AGPR weights + distance-8 h pipeline. Remaining cost:
// per-group 4-read asm block serializes ~10 cyc against the ~8-cyc-latency
// FMA chain. Fix: software-pipeline the WEIGHT reads one group ahead, ONE
// read interleaved after each chain FMA (reads issue inside the chain's
// dep-stall slots). ds refill stays at group end. Chain order unchanged.

#define SEQ 2048
#define BATCH 64
#define HID 256
#define BH 16384  // BATCH*HID

// Eigen/XLA fast-tanh f32, FMA evaluation, clamp 7.99881172180175781.
__device__ __forceinline__ float tanh_xla(float x) {
  const float kClamp = 7.99881172180175781f;
  float xc = fminf(fmaxf(x, -kClamp), kClamp);
  float x2 = __fmul_rn(xc, xc);
  float p = __fmaf_rn(x2, -2.76076847742355e-16f, 2.00018790482477e-13f);
  p = __fmaf_rn(x2, p, -8.60467152213735e-11f);
  p = __fmaf_rn(x2, p, 5.12229709037114e-08f);
  p = __fmaf_rn(x2, p, 1.48572235717979e-05f);
  p = __fmaf_rn(x2, p, 6.37261928875436e-04f);
  p = __fmaf_rn(x2, p, 4.89352455891786e-03f);
  p = __fmul_rn(xc, p);
  float q = __fmaf_rn(x2, 1.19825839466702e-06f, 1.18534705686654e-04f);
  q = __fmaf_rn(x2, q, 2.26843463243900e-03f);
  q = __fmaf_rn(x2, q, 4.89352518554385e-03f);
  float r = __fdiv_rn(p, q);
  return (fabsf(x) < 0.0004f) ? x : r;
}

// ---------------------------------------------------------------------------
// K1: xp = X @ Ux + bh. Per element: single-acc ascending-i FMA chain
// (Eigen order), then one fadd for bias. BIT-EXACT — do not reorder.
// ---------------------------------------------------------------------------
__global__ __launch_bounds__(256) void xp_dot_kernel(
    const float* __restrict__ X, const float* __restrict__ Ux,
    const float* __restrict__ bh, float* __restrict__ XP) {
  __shared__ float xs[8][256];

  const int tid = threadIdx.x;
  const size_t row0 = (size_t)blockIdx.x * 8;

  const float4* src = (const float4*)(X + row0 * 256);
  float4* dst = (float4*)&xs[0][0];
  dst[tid] = src[tid];
  dst[256 + tid] = src[256 + tid];
  __syncthreads();

  const int h = tid;
  float acc[8] = {0.f, 0.f, 0.f, 0.f, 0.f, 0.f, 0.f, 0.f};

#pragma unroll 4
  for (int i = 0; i < 256; ++i) {
    float u = Ux[i * 256 + h];
#pragma unroll
    for (int r = 0; r < 8; ++r)
      acc[r] = __fmaf_rn(xs[r][i], u, acc[r]);   // ascending i, single acc
  }

  const float b = bh[h];
#pragma unroll
  for (int r = 0; r < 8; ++r)
    XP[(row0 + r) * 256 + h] = __fadd_rn(acc[r], b);
}

// ---------------------------------------------------------------------------
// K2: scan. One block per batch row; thread j owns column j. Wh[:,j] in AGPRs
// a0..a255. Weight reads pipelined ONE GROUP AHEAD, one read per FMA slot;
// h reads pipelined distance 8 (hb0..hb7). Chain: ascending k, single acc.
// ---------------------------------------------------------------------------
#define WLD(K) { float wt = Wh[(K) * 256 + j]; \
  asm volatile("v_accvgpr_write_b32 a" #K ", %0" :: "v"(wt) : "a" #K); }
#define WLD4(K0,K1,K2,K3) WLD(K0) WLD(K1) WLD(K2) WLD(K3)

#define WR1(K, D) asm volatile("v_accvgpr_read_b32 %0, a" #K : "=v"(D));

// Full group: 4 chain FMAs on current weights CW*, interleaved single reads
// of next group's weights (AGPR NK*) into NW*, then h refill from h4[NQ].
#define GRPF(HB, CW0,CW1,CW2,CW3, NK0,NK1,NK2,NK3, NW0,NW1,NW2,NW3, NQ) { \
  acc = __fmaf_rn(HB.x, CW0, acc); WR1(NK0, NW0) \
  acc = __fmaf_rn(HB.y, CW1, acc); WR1(NK1, NW1) \
  acc = __fmaf_rn(HB.z, CW2, acc); WR1(NK2, NW2) \
  acc = __fmaf_rn(HB.w, CW3, acc); WR1(NK3, NW3) \
  HB = h4[NQ]; }

// No-refill group (h pipeline exhausted).
#define GRPN(HB, CW0,CW1,CW2,CW3, NK0,NK1,NK2,NK3, NW0,NW1,NW2,NW3) { \
  acc = __fmaf_rn(HB.x, CW0, acc); WR1(NK0, NW0) \
  acc = __fmaf_rn(HB.y, CW1, acc); WR1(NK1, NW1) \
  acc = __fmaf_rn(HB.z, CW2, acc); WR1(NK2, NW2) \
  acc = __fmaf_rn(HB.w, CW3, acc); WR1(NK3, NW3) }

// End group: FMAs only.
#define GRPE(HB, CW0,CW1,CW2,CW3) { \
  acc = __fmaf_rn(HB.x, CW0, acc); \
  acc = __fmaf_rn(HB.y, CW1, acc); \
  acc = __fmaf_rn(HB.z, CW2, acc); \
  acc = __fmaf_rn(HB.w, CW3, acc); }

__global__ __launch_bounds__(256)
__attribute__((amdgpu_waves_per_eu(1, 1)))
void scan_xla_kernel(
    const float* __restrict__ Wh, const float* __restrict__ h0,
    float* __restrict__ xpH, float* __restrict__ hfinal) {
  __shared__ float hbuf0[256];
  __shared__ float hbuf1[256];

  const int b = blockIdx.x;
  const int j = threadIdx.x;

  // ---- load Wh[:,j] into a0..a255 ----
  WLD4(0,1,2,3)       WLD4(4,5,6,7)       WLD4(8,9,10,11)     WLD4(12,13,14,15)
  WLD4(16,17,18,19)   WLD4(20,21,22,23)   WLD4(24,25,26,27)   WLD4(28,29,30,31)
  WLD4(32,33,34,35)   WLD4(36,37,38,39)   WLD4(40,41,42,43)   WLD4(44,45,46,47)
  WLD4(48,49,50,51)   WLD4(52,53,54,55)   WLD4(56,57,58,59)   WLD4(60,61,62,63)
  WLD4(64,65,66,67)   WLD4(68,69,70,71)   WLD4(72,73,74,75)   WLD4(76,77,78,79)
  WLD4(80,81,82,83)   WLD4(84,85,86,87)   WLD4(88,89,90,91)   WLD4(92,93,94,95)
  WLD4(96,97,98,99)   WLD4(100,101,102,103) WLD4(104,105,106,107) WLD4(108,109,110,111)
  WLD4(112,113,114,115) WLD4(116,117,118,119) WLD4(120,121,122,123) WLD4(124,125,126,127)
  WLD4(128,129,130,131) WLD4(132,133,134,135) WLD4(136,137,138,139) WLD4(140,141,142,143)
  WLD4(144,145,146,147) WLD4(148,149,150,151) WLD4(152,153,154,155) WLD4(156,157,158,159)
  WLD4(160,161,162,163) WLD4(164,165,166,167) WLD4(168,169,170,171) WLD4(172,173,174,175)
  WLD4(176,177,178,179) WLD4(180,181,182,183) WLD4(184,185,186,187) WLD4(188,189,190,191)
  WLD4(192,193,194,195) WLD4(196,197,198,199) WLD4(200,201,202,203) WLD4(204,205,206,207)
  WLD4(208,209,210,211) WLD4(212,213,214,215) WLD4(216,217,218,219) WLD4(220,221,222,223)
  WLD4(224,225,226,227) WLD4(228,229,230,231) WLD4(232,233,234,235) WLD4(236,237,238,239)
  WLD4(240,241,242,243) WLD4(244,245,246,247) WLD4(248,249,250,251) WLD4(252,253,254,255)

  hbuf0[j] = h0[b * 256 + j];
  __syncthreads();

  float xp_cur = xpH[(size_t)b * 256 + j];  // xp[t=0]
  float hn_prev = 0.f;
  const float* cur = hbuf0;
  float* nxt = hbuf1;

  for (int t = 0; t < SEQ; ++t) {
    // Global store/load issued first; retire under the chain.
    if (t > 0)
      xpH[(size_t)(t - 1) * BH + b * 256 + j] = hn_prev;
    float xp_next = (t + 1 < SEQ) ? xpH[(size_t)(t + 1) * BH + b * 256 + j] : 0.f;

    const float4* h4 = (const float4*)cur;
    // h pipeline prologue (8 deep).
    float4 hb0 = h4[0], hb1 = h4[1], hb2 = h4[2], hb3 = h4[3];
    float4 hb4 = h4[4], hb5 = h4[5], hb6 = h4[6], hb7 = h4[7];

    // Weight pipeline prologue: group 0 -> wa.
    float wa0, wa1, wa2, wa3, wb0, wb1, wb2, wb3;
    WR1(0, wa0) WR1(1, wa1) WR1(2, wa2) WR1(3, wa3)

    float acc = 0.f;
    // g=0..55: full groups (h refill).   even g: current=wa, next->wb.
    GRPF(hb0, wa0,wa1,wa2,wa3,   4,5,6,7,     wb0,wb1,wb2,wb3,  8)
    GRPF(hb1, wb0,wb1,wb2,wb3,   8,9,10,11,   wa0,wa1,wa2,wa3,  9)
    GRPF(hb2, wa0,wa1,wa2,wa3,   12,13,14,15, wb0,wb1,wb2,wb3, 10)
    GRPF(hb3, wb0,wb1,wb2,wb3,   16,17,18,19, wa0,wa1,wa2,wa3, 11)
    GRPF(hb4, wa0,wa1,wa2,wa3,   20,21,22,23, wb0,wb1,wb2,wb3, 12)
    GRPF(hb5, wb0,wb1,wb2,wb3,   24,25,26,27, wa0,wa1,wa2,wa3, 13)
    GRPF(hb6, wa0,wa1,wa2,wa3,   28,29,30,31, wb0,wb1,wb2,wb3, 14)
    GRPF(hb7, wb0,wb1,wb2,wb3,   32,33,34,35, wa0,wa1,wa2,wa3, 15)
    GRPF(hb0, wa0,wa1,wa2,wa3,   36,37,38,39, wb0,wb1,wb2,wb3, 16)
    GRPF(hb1, wb0,wb1,wb2,wb3,   40,41,42,43, wa0,wa1,wa2,wa3, 17)
    GRPF(hb2, wa0,wa1,wa2,wa3,   44,45,46,47, wb0,wb1,wb2,wb3, 18)
    GRPF(hb3, wb0,wb1,wb2,wb3,   48,49,50,51, wa0,wa1,wa2,wa3, 19)
    GRPF(hb4, wa0,wa1,wa2,wa3,   52,53,54,55, wb0,wb1,wb2,wb3, 20)
    GRPF(hb5, wb0,wb1,wb2,wb3,   56,57,58,59, wa0,wa1,wa2,wa3, 21)
    GRPF(hb6, wa0,wa1,wa2,wa3,   60,61,62,63, wb0,wb1,wb2,wb3, 22)
    GRPF(hb7, wb0,wb1,wb2,wb3,   64,65,66,67, wa0,wa1,wa2,wa3, 23)
    GRPF(hb0, wa0,wa1,wa2,wa3,   68,69,70,71, wb0,wb1,wb2,wb3, 24)
    GRPF(hb1, wb0,wb1,wb2,wb3,   72,73,74,75, wa0,wa1,wa2,wa3, 25)
    GRPF(hb2, wa0,wa1,wa2,wa3,   76,77,78,79, wb0,wb1,wb2,wb3, 26)
    GRPF(hb3, wb0,wb1,wb2,wb3,   80,81,82,83, wa0,wa1,wa2,wa3, 27)
    GRPF(hb4, wa0,wa1,wa2,wa3,   84,85,86,87, wb0,wb1,wb2,wb3, 28)
    GRPF(hb5, wb0,wb1,wb2,wb3,   88,89,90,91, wa0,wa1,wa2,wa3, 29)
    GRPF(hb6, wa0,wa1,wa2,wa3,   92,93,94,95, wb0,wb1,wb2,wb3, 30)
    GRPF(hb7, wb0,wb1,wb2,wb3,   96,97,98,99, wa0,wa1,wa2,wa3, 31)
    GRPF(hb0, wa0,wa1,wa2,wa3,   100,101,102,103, wb0,wb1,wb2,wb3, 32)
    GRPF(hb1, wb0,wb1,wb2,wb3,   104,105,106,107, wa0,wa1,wa2,wa3, 33)
    GRPF(hb2, wa0,wa1,wa2,wa3,   108,109,110,111, wb0,wb1,wb2,wb3, 34)
    GRPF(hb3, wb0,wb1,wb2,wb3,   112,113,114,115, wa0,wa1,wa2,wa3, 35)
    GRPF(hb4, wa0,wa1,wa2,wa3,   116,117,118,119, wb0,wb1,wb2,wb3, 36)
    GRPF(hb5, wb0,wb1,wb2,wb3,   120,121,122,123, wa0,wa1,wa2,wa3, 37)
    GRPF(hb6, wa0,wa1,wa2,wa3,   124,125,126,127, wb0,wb1,wb2,wb3, 38)
    GRPF(hb7, wb0,wb1,wb2,wb3,   128,129,130,131, wa0,wa1,wa2,wa3, 39)
    GRPF(hb0, wa0,wa1,wa2,wa3,   132,133,134,135, wb0,wb1,wb2,wb3, 40)
    GRPF(hb1, wb0,wb1,wb2,wb3,   136,137,138,139, wa0,wa1,wa2,wa3, 41)
    GRPF(hb2, wa0,wa1,wa2,wa3,   140,141,142,143, wb0,wb1,wb2,wb3, 42)
    GRPF(hb3, wb0,wb1,wb2,wb3,   144,145,146,147, wa0,wa1,wa2,wa3, 43)
    GRPF(hb4, wa0,wa1,wa2,wa3,   148,149,150,151, wb0,wb1,wb2,wb3, 44)
    GRPF(hb5, wb0,wb1,wb2,wb3,   152,153,154,155, wa0,wa1,wa2,wa3, 45)
    GRPF(hb6, wa0,wa1,wa2,wa3,   156,157,158,159, wb0,wb1,wb2,wb3, 46)
    GRPF(hb7, wb0,wb1,wb2,wb3,   160,161,162,163, wa0,wa1,wa2,wa3, 47)
    GRPF(hb0, wa0,wa1,wa2,wa3,   164,165,166,167, wb0,wb1,wb2,wb3, 48)
    GRPF(hb1, wb0,wb1,wb2,wb3,   168,169,170,171, wa0,wa1,wa2,wa3, 49)
    GRPF(hb2, wa0,wa1,wa2,wa3,   172,173,174,175, wb0,wb1,wb2,wb3, 50)
    GRPF(hb3, wb0,wb1,wb2,wb3,   176,177,178,179, wa0,wa1,wa2,wa3, 51)
    GRPF(hb4, wa0,wa1,wa2,wa3,   180,181,182,183, wb0,wb1,wb2,wb3, 52)
    GRPF(hb5, wb0,wb1,wb2,wb3,   184,185,186,187, wa0,wa1,wa2,wa3, 53)
    GRPF(hb6, wa0,wa1,wa2,wa3,   188,189,190,191, wb0,wb1,wb2,wb3, 54)
    GRPF(hb7, wb0,wb1,wb2,wb3,   192,193,194,195, wa0,wa1,wa2,wa3, 55)
    GRPF(hb0, wa0,wa1,wa2,wa3,   196,197,198,199, wb0,wb1,wb2,wb3, 56)
    GRPF(hb1, wb0,wb1,wb2,wb3,   200,201,202,203, wa0,wa1,wa2,wa3, 57)
    GRPF(hb2, wa0,wa1,wa2,wa3,   204,205,206,207, wb0,wb1,wb2,wb3, 58)
    GRPF(hb3, wb0,wb1,wb2,wb3,   208,209,210,211, wa0,wa1,wa2,wa3, 59)
    GRPF(hb4, wa0,wa1,wa2,wa3,   212,213,214,215, wb0,wb1,wb2,wb3, 60)
    GRPF(hb5, wb0,wb1,wb2,wb3,   216,217,218,219, wa0,wa1,wa2,wa3, 61)
    GRPF(hb6, wa0,wa1,wa2,wa3,   220,221,222,223, wb0,wb1,wb2,wb3, 62)
    GRPF(hb7, wb0,wb1,wb2,wb3,   224,225,226,227, wa0,wa1,wa2,wa3, 63)
    // g=56..62: no h refill.
    GRPN(hb0, wa0,wa1,wa2,wa3,   228,229,230,231, wb0,wb1,wb2,wb3)
    GRPN(hb1, wb0,wb1,wb2,wb3,   232,233,234,235, wa0,wa1,wa2,wa3)
    GRPN(hb2, wa0,wa1,wa2,wa3,   236,237,238,239, wb0,wb1,wb2,wb3)
    GRPN(hb3, wb0,wb1,wb2,wb3,   240,241,242,243, wa0,wa1,wa2,wa3)
    GRPN(hb4, wa0,wa1,wa2,wa3,   244,245,246,247, wb0,wb1,wb2,wb3)
    GRPN(hb5, wb0,wb1,wb2,wb3,   248,249,250,251, wa0,wa1,wa2,wa3)
    GRPN(hb6, wa0,wa1,wa2,wa3,   252,253,254,255, wb0,wb1,wb2,wb3)
    // g=63.
    GRPE(hb7, wb0,wb1,wb2,wb3)

    float z = __fadd_rn(xp_cur, acc);
    float hn = tanh_xla(z);

    nxt[j] = hn;
    __syncthreads();      // one barrier per step (double-buffered h)

    const float* tmp = cur; cur = nxt; nxt = (float*)tmp;
    xp_cur = xp_next;
    hn_prev = hn;
  }

  xpH[(size_t)(SEQ - 1) * BH + b * 256 + j] = hn_prev;
  hfinal[b * 256 + j] = hn_prev;
}

// ---------------------------------------------------------------------------
// K3: in-place fp32 GEMM: rows of HO (M x 256) -> row @ Vo + co.
// Outside the feedback loop => rounding free. Block stages its own 64 rows
// in LDS then overwrites exactly those rows (race-free).
// ---------------------------------------------------------------------------
__global__ __launch_bounds__(256) void gemm_inplace_kernel(
    float* __restrict__ HO, const float* __restrict__ Vo,
    const float* __restrict__ co) {
  __shared__ float Hs[64][260];
  __shared__ float Bs[32][64];

  const int tid = threadIdx.x;
  const int bm = blockIdx.x;
  float* base = HO + (size_t)bm * 64 * 256;

#pragma unroll
  for (int l = 0; l < 16; ++l) {
    int idx = l * 256 + tid;
    int r = idx >> 6;
    int c4 = idx & 63;
    float4 v = *(const float4*)&base[r * 256 + c4 * 4];
    *(float4*)&Hs[r][c4 * 4] = v;
  }

  const int tr = tid >> 4;
  const int tc = tid & 15;

  for (int bn = 0; bn < 4; ++bn) {
    float acc[4][4];
#pragma unroll
    for (int i = 0; i < 4; ++i)
#pragma unroll
      for (int j = 0; j < 4; ++j) acc[i][j] = 0.f;

    for (int kt = 0; kt < 256; kt += 32) {
      __syncthreads();
#pragma unroll
      for (int l = 0; l < 2; ++l) {
        int idx = tid * 2 + l;
        int k2 = idx >> 4;
        int nn = (idx & 15) << 2;
        float4 bv = *(const float4*)&Vo[(size_t)(kt + k2) * 256 + bn * 64 + nn];
        *(float4*)&Bs[k2][nn] = bv;
      }
      __syncthreads();
#pragma unroll
      for (int k = 0; k < 32; ++k) {
        float4 bq = *(const float4*)&Bs[k][tc * 4];
        float bv[4] = {bq.x, bq.y, bq.z, bq.w};
#pragma unroll
        for (int i = 0; i < 4; ++i) {
          float a = Hs[tr * 4 + i][kt + k];
#pragma unroll
          for (int j = 0; j < 4; ++j) acc[i][j] += a * bv[j];
        }
      }
    }

    const float4 cb = *(const float4*)&co[bn * 64 + tc * 4];
    const float cv[4] = {cb.x, cb.y, cb.z, cb.w};
#pragma unroll
    for (int i = 0; i < 4; ++i) {
      float4 o;
      o.x = acc[i][0] + cv[0];
      o.y = acc[i][1] + cv[1];
      o.z = acc[i][2] + cv[2];
      o.w = acc[i][3] + cv[3];
      *(float4*)&base[(tr * 4 + i) * 256 + bn * 64 + tc * 4] = o;
    }
  }
}

extern "C" void kernel_launch(void* const* d_in, const int* in_sizes, int n_in,
                              void* d_out, int out_size, void* d_ws, size_t ws_size,
                              hipStream_t stream) {
  const float* inputs = (const float*)d_in[0];
  const float* h0     = (const float*)d_in[1];
  const float* Wh     = (const float*)d_in[2];
  const float* Ux     = (const float*)d_in[3];
  const float* bh     = (const float*)d_in[4];
  const float* Vo     = (const float*)d_in[5];
  const float* co     = (const float*)d_in[6];

  float* out = (float*)d_out;                       // outputs (S,B,O)
  float* hfinal = out + (size_t)SEQ * BATCH * 256;  // ht_final (B,H)
  (void)d_ws; (void)ws_size;

  const int M = SEQ * BATCH;  // 131072 rows

  // K1: xp (Eigen-order FMA chain + bias add) -> d_out outputs region
  xp_dot_kernel<<<M / 8, 256, 0, stream>>>(inputs, Ux, bh, out);

  // K2: XLA-exact scan, AGPR weights (pipelined reads) + distance-8 h pipeline.
  scan_xla_kernel<<<BATCH, 256, 0, stream>>>(Wh, h0, out, hfinal);

  // K3: in-place outputs = H @ Vo + co.
  gemm_inplace_kernel<<<M / 64, 256, 0, stream>>>(out, Vo, co);
}